// Round 9
// baseline (174.193 us; speedup 1.0000x reference)
//
#include <hip/hip_runtime.h>

// SSIM loss, fused, fp32. Row-paired packed H-conv (f32x2 temporaries only),
// SCALAR float[7] even/odd ring (round-8-proven promotion pattern).
// Round-9 changes vs round-8 (math core identical):
//  - 1024 blocks x 256 threads; block = one 32-row strip, 4 waves = 4 col
//    segments sharing the same rows (L2 line sharing, round-3-proven).
//  - prefetch depth 3: hold pairs li+1,li+2 in regs, load li+3.
//  - __launch_bounds__(256,4) for 16 waves/CU.

typedef float f32x2 __attribute__((ext_vector_type(2)));

#define IMG_W 256
#define IMG_H 256
#define N_PIX (128.0f * 256.0f * 256.0f)
#define NPAIR 22  // staged row-pairs: rows rs-6 .. rs+37

static __device__ __forceinline__ f32x2 fma2(f32x2 a, f32x2 b, f32x2 c) {
  return __builtin_elementwise_fma(a, b, c);
}

__global__ void ssim_init(float* out) { out[0] = 1.0f; }

__global__ __launch_bounds__(256, 4) void ssim_main(
    const float* __restrict__ img1, const float* __restrict__ img2,
    float* __restrict__ out) {
  // 1D Gaussian, sigma=1.5, 11 taps (identical constants to passing rounds)
  const float W0 = 0.00102838f, W1 = 0.00759873f, W2 = 0.03600077f,
              W3 = 0.10936070f, W4 = 0.21300543f, W5 = 0.26601173f,
              W6 = 0.21300543f, W7 = 0.10936070f, W8 = 0.03600077f,
              W9 = 0.00759873f, W10 = 0.00102838f;
  const float WH[11] = {W0, W1, W2, W3, W4, W5, W6, W7, W8, W9, W10};

  __shared__ f32x2 LSX[4][2][128];  // [wave][dbuf][col entry] img1 row-pairs
  __shared__ f32x2 LSY[4][2][128];  // img2 row-pairs
  __shared__ float wsum[4];

  const int tid = threadIdx.x;
  const int lane = tid & 63;
  const int wid = tid >> 6;
  // 4 waves of a block = same strip (rows), 4 col segments -> L2 sharing
  const int gw = __builtin_amdgcn_readfirstlane(blockIdx.x * 4 + wid);
  const int img = gw >> 5;         // 32 waves per image
  const int rem = gw & 31;
  const int rs = (rem >> 2) << 5;  // strip start row (0,32,..,224)
  const int cs = (rem & 3) << 6;   // col segment (0,64,128,192)
  const int r0p = rs - 6;          // first staged row (even)
  const char* q1 = (const char*)(img1 + (size_t)img * (IMG_W * IMG_H));
  const char* q2 = (const char*)(img2 + (size_t)img * (IMG_W * IMG_H));

  // per-lane column byte offsets (clamped) + masks; row-invariant
  const int c0 = cs - 8 + lane;  // only underflow possible
  const int c1 = c0 + 64;        // only overflow possible
  const float cm0 = (c0 >= 0) ? 1.f : 0.f;
  const float cm1 = (c1 < IMG_W) ? 1.f : 0.f;
  const int co0 = (c0 < 0 ? 0 : c0) << 2;
  const int co1 = (c1 > IMG_W - 1 ? IMG_W - 1 : c1) << 2;
  const f32x2 vm0 = {cm0, cm0};
  const f32x2 vm1 = {cm1, cm1};

#define CLAMPR(r) ((r) < 0 ? 0 : ((r) > IMG_H - 1 ? IMG_H - 1 : (r)))
#define PAIRLOAD(P, X0, Y0, X1, Y1)                                           \
  do {                                                                        \
    const int ra_ = r0p + 2 * (P), rb_ = ra_ + 1;                             \
    const char* a1_ = q1 + (CLAMPR(ra_) << 10);                               \
    const char* b1_ = q1 + (CLAMPR(rb_) << 10);                               \
    const char* a2_ = q2 + (CLAMPR(ra_) << 10);                               \
    const char* b2_ = q2 + (CLAMPR(rb_) << 10);                               \
    X0 = (f32x2){*(const float*)(a1_ + co0), *(const float*)(b1_ + co0)} * vm0; \
    Y0 = (f32x2){*(const float*)(a2_ + co0), *(const float*)(b2_ + co0)} * vm0; \
    X1 = (f32x2){*(const float*)(a1_ + co1), *(const float*)(b1_ + co1)} * vm1; \
    Y1 = (f32x2){*(const float*)(a2_ + co1), *(const float*)(b2_ + co1)} * vm1; \
  } while (0)

  // ring: 7 pair-slots x 5 channels, split even/odd as SCALAR arrays (70 f32)
  float R1e[7], R1o[7], R2e[7], R2o[7], R11e[7], R11o[7], R22e[7], R22o[7],
      R12e[7], R12o[7];
  f32x2 accv = {0.f, 0.f};

  // prologue: stage pair0 into buf0; h <- pair1 (stage next iter); g <- pair2
  f32x2 hx0, hy0, hx1, hy1, gx0, gy0, gx1, gy1, nx0, ny0, nx1, ny1;
  PAIRLOAD(0, hx0, hy0, hx1, hy1);
  LSX[wid][0][lane] = hx0; LSY[wid][0][lane] = hy0;
  LSX[wid][0][64 + lane] = hx1; LSY[wid][0][64 + lane] = hy1;
  PAIRLOAD(1, hx0, hy0, hx1, hy1);
  PAIRLOAD(2, gx0, gy0, gx1, gy1);

  for (int bl = 0; bl < 28; bl += 7) {
#pragma unroll
    for (int u = 0; u < 7; ++u) {
      const int li = bl + u;  // pair index; ring slot is `u` (bl % 7 == 0)
      if (li < NPAIR) {
        // (1) issue loads for pair li+3 (two full iterations of cover)
        if (li + 3 < NPAIR) {
          PAIRLOAD(li + 3, nx0, ny0, nx1, ny1);
        } else {
          nx0 = (f32x2){0, 0}; ny0 = (f32x2){0, 0};
          nx1 = (f32x2){0, 0}; ny1 = (f32x2){0, 0};
        }
        // (2) stage held pair li+1 into the other buffer
        if (li + 1 < NPAIR) {
          f32x2* wx = &LSX[wid][(li + 1) & 1][0];
          f32x2* wy = &LSY[wid][(li + 1) & 1][0];
          wx[lane] = hx0; wy[lane] = hy0;
          wx[64 + lane] = hx1; wy[64 + lane] = hy1;
        }
        // (3) packed horizontal 11-tap conv on row-pair li
        {
          const f32x2* bx = &LSX[wid][li & 1][lane];
          const f32x2* by = &LSY[wid][li & 1][lane];
          f32x2 s1 = {0, 0}, s2 = {0, 0}, s11 = {0, 0}, s22 = {0, 0},
                s12 = {0, 0};
#pragma unroll
          for (int k = 0; k < 11; ++k) {
            const f32x2 vx = bx[3 + k];
            const f32x2 vy = by[3 + k];
            const f32x2 tx = vx * WH[k];
            const f32x2 ty = vy * WH[k];
            s1 += tx; s2 += ty;
            s11 = fma2(tx, vx, s11);
            s22 = fma2(ty, vy, s22);
            s12 = fma2(tx, vy, s12);
          }
          const int ra = r0p + 2 * li;
          const float vr = ((unsigned)ra < IMG_H) ? 1.f : 0.f;
          const f32x2 vmr = {vr, vr};
          s1 *= vmr; s2 *= vmr; s11 *= vmr; s22 *= vmr; s12 *= vmr;
          // split into scalar even/odd ring slots (index u: compile-time)
          R1e[u] = s1.x;  R1o[u] = s1.y;
          R2e[u] = s2.x;  R2o[u] = s2.y;
          R11e[u] = s11.x; R11o[u] = s11.y;
          R22e[u] = s22.x; R22o[u] = s22.y;
          R12e[u] = s12.x; R12o[u] = s12.y;
        }
        // (4) scalar vertical conv + packed SSIM for out-pair i = li-6
        if (li >= 6) {
#define S_(m) ((u + 1 + (m)) % 7)
#define VERT(E, O, V0, V1)                              \
  do {                                                  \
    float v0_ = W0 * O[S_(0)];                          \
    v0_ = fmaf(W1, E[S_(1)], v0_);                      \
    v0_ = fmaf(W2, O[S_(1)], v0_);                      \
    v0_ = fmaf(W3, E[S_(2)], v0_);                      \
    v0_ = fmaf(W4, O[S_(2)], v0_);                      \
    v0_ = fmaf(W5, E[S_(3)], v0_);                      \
    v0_ = fmaf(W6, O[S_(3)], v0_);                      \
    v0_ = fmaf(W7, E[S_(4)], v0_);                      \
    v0_ = fmaf(W8, O[S_(4)], v0_);                      \
    v0_ = fmaf(W9, E[S_(5)], v0_);                      \
    v0_ = fmaf(W10, O[S_(5)], v0_);                     \
    V0 = v0_;                                           \
    float v1_ = W0 * E[S_(1)];                          \
    v1_ = fmaf(W1, O[S_(1)], v1_);                      \
    v1_ = fmaf(W2, E[S_(2)], v1_);                      \
    v1_ = fmaf(W3, O[S_(2)], v1_);                      \
    v1_ = fmaf(W4, E[S_(3)], v1_);                      \
    v1_ = fmaf(W5, O[S_(3)], v1_);                      \
    v1_ = fmaf(W6, E[S_(4)], v1_);                      \
    v1_ = fmaf(W7, O[S_(4)], v1_);                      \
    v1_ = fmaf(W8, E[S_(5)], v1_);                      \
    v1_ = fmaf(W9, O[S_(5)], v1_);                      \
    v1_ = fmaf(W10, E[S_(6)], v1_);                     \
    V1 = v1_;                                           \
  } while (0)
          float m1a, m1b, m2a, m2b, e11a, e11b, e22a, e22b, e12a, e12b;
          VERT(R1e, R1o, m1a, m1b);
          VERT(R2e, R2o, m2a, m2b);
          VERT(R11e, R11o, e11a, e11b);
          VERT(R22e, R22o, e22a, e22b);
          VERT(R12e, R12o, e12a, e12b);
#undef VERT
#undef S_
          const f32x2 m1 = {m1a, m1b}, m2 = {m2a, m2b};
          const f32x2 e11 = {e11a, e11b}, e22 = {e22a, e22b},
                      e12 = {e12a, e12b};
          const f32x2 c1v = {1e-4f, 1e-4f}, c2v = {9e-4f, 9e-4f};
          const f32x2 mu11 = m1 * m1, mu22 = m2 * m2, mu12 = m1 * m2;
          const f32x2 sg11 = e11 - mu11, sg22 = e22 - mu22, sg12 = e12 - mu12;
          const f32x2 num = (mu12 * 2.0f + c1v) * (sg12 * 2.0f + c2v);
          const f32x2 den = (mu11 + mu22 + c1v) * (sg11 + sg22 + c2v);
          float t0 = __builtin_amdgcn_rcpf(den.x);
          t0 = t0 * fmaf(-den.x, t0, 2.f);  // one Newton step
          float t1 = __builtin_amdgcn_rcpf(den.y);
          t1 = t1 * fmaf(-den.y, t1, 2.f);
          accv = fma2(num, (f32x2){t0, t1}, accv);
        }
        // rotate held pairs: h <- g <- n
        hx0 = gx0; hy0 = gy0; hx1 = gx1; hy1 = gy1;
        gx0 = nx0; gy0 = ny0; gx1 = nx1; gy1 = ny1;
      }
    }
  }

  // reduction: wave shuffle -> block LDS -> one atomic per block
  float tot = accv.x + accv.y;
  tot += __shfl_xor(tot, 1);
  tot += __shfl_xor(tot, 2);
  tot += __shfl_xor(tot, 4);
  tot += __shfl_xor(tot, 8);
  tot += __shfl_xor(tot, 16);
  tot += __shfl_xor(tot, 32);
  if (lane == 0) wsum[wid] = tot;
  __syncthreads();
  if (tid == 0) {
    const float s = wsum[0] + wsum[1] + wsum[2] + wsum[3];
    atomicAdd(out, s * (-1.0f / N_PIX));
  }
}

extern "C" void kernel_launch(void* const* d_in, const int* in_sizes, int n_in,
                              void* d_out, int out_size, void* d_ws,
                              size_t ws_size, hipStream_t stream) {
  const float* img1 = (const float*)d_in[0];
  const float* img2 = (const float*)d_in[1];
  float* out = (float*)d_out;
  ssim_init<<<1, 1, 0, stream>>>(out);
  ssim_main<<<1024, 256, 0, stream>>>(img1, img2, out);
}

// Round 12
// 138.711 us; speedup vs baseline: 1.2558x; 1.2558x over previous
//
#include <hip/hip_runtime.h>

// SSIM loss, fused, fp32. Row-paired packed H-conv (f32x2 temporaries only),
// SCALAR float[7] even/odd ring (round-8-proven promotion pattern).
// Round-10 = round-8 math core EXACTLY + round-3 geometry:
//  - 1024 blocks x 256 threads; block = one 32-row strip, 4 waves = 4 col
//    segments sharing rows (L2 sharing: round-3 fetched 42MB vs r8's 92MB).
//  - prefetch depth 2 (round-8's h-only rotation; fits in 84 VGPRs).
//  - __launch_bounds__(256) with NO min-waves arg (rounds 2/3: no spill).

typedef float f32x2 __attribute__((ext_vector_type(2)));

#define IMG_W 256
#define IMG_H 256
#define N_PIX (128.0f * 256.0f * 256.0f)
#define NPAIR 22  // staged row-pairs: rows rs-6 .. rs+37

static __device__ __forceinline__ f32x2 fma2(f32x2 a, f32x2 b, f32x2 c) {
  return __builtin_elementwise_fma(a, b, c);
}

__global__ void ssim_init(float* out) { out[0] = 1.0f; }

__global__ __launch_bounds__(256) void ssim_main(
    const float* __restrict__ img1, const float* __restrict__ img2,
    float* __restrict__ out) {
  // 1D Gaussian, sigma=1.5, 11 taps (identical constants to passing rounds)
  const float W0 = 0.00102838f, W1 = 0.00759873f, W2 = 0.03600077f,
              W3 = 0.10936070f, W4 = 0.21300543f, W5 = 0.26601173f,
              W6 = 0.21300543f, W7 = 0.10936070f, W8 = 0.03600077f,
              W9 = 0.00759873f, W10 = 0.00102838f;
  const float WH[11] = {W0, W1, W2, W3, W4, W5, W6, W7, W8, W9, W10};

  __shared__ f32x2 LSX[4][2][128];  // [wave][dbuf][col entry] img1 row-pairs
  __shared__ f32x2 LSY[4][2][128];  // img2 row-pairs
  __shared__ float wsum[4];

  const int tid = threadIdx.x;
  const int lane = tid & 63;
  const int wid = tid >> 6;
  // 4 waves of a block = same strip (rows), 4 col segments -> L2 sharing
  const int gw = __builtin_amdgcn_readfirstlane(blockIdx.x * 4 + wid);
  const int img = gw >> 5;         // 32 waves per image
  const int rem = gw & 31;
  const int rs = (rem >> 2) << 5;  // strip start row (0,32,..,224)
  const int cs = (rem & 3) << 6;   // col segment (0,64,128,192)
  const int r0p = rs - 6;          // first staged row (even)
  const char* q1 = (const char*)(img1 + (size_t)img * (IMG_W * IMG_H));
  const char* q2 = (const char*)(img2 + (size_t)img * (IMG_W * IMG_H));

  // per-lane column byte offsets (clamped) + masks; row-invariant
  const int c0 = cs - 8 + lane;  // only underflow possible
  const int c1 = c0 + 64;        // only overflow possible
  const float cm0 = (c0 >= 0) ? 1.f : 0.f;
  const float cm1 = (c1 < IMG_W) ? 1.f : 0.f;
  const int co0 = (c0 < 0 ? 0 : c0) << 2;
  const int co1 = (c1 > IMG_W - 1 ? IMG_W - 1 : c1) << 2;
  const f32x2 vm0 = {cm0, cm0};
  const f32x2 vm1 = {cm1, cm1};

#define CLAMPR(r) ((r) < 0 ? 0 : ((r) > IMG_H - 1 ? IMG_H - 1 : (r)))
#define PAIRLOAD(P, X0, Y0, X1, Y1)                                           \
  do {                                                                        \
    const int ra_ = r0p + 2 * (P), rb_ = ra_ + 1;                             \
    const char* a1_ = q1 + (CLAMPR(ra_) << 10);                               \
    const char* b1_ = q1 + (CLAMPR(rb_) << 10);                               \
    const char* a2_ = q2 + (CLAMPR(ra_) << 10);                               \
    const char* b2_ = q2 + (CLAMPR(rb_) << 10);                               \
    X0 = (f32x2){*(const float*)(a1_ + co0), *(const float*)(b1_ + co0)} * vm0; \
    Y0 = (f32x2){*(const float*)(a2_ + co0), *(const float*)(b2_ + co0)} * vm0; \
    X1 = (f32x2){*(const float*)(a1_ + co1), *(const float*)(b1_ + co1)} * vm1; \
    Y1 = (f32x2){*(const float*)(a2_ + co1), *(const float*)(b2_ + co1)} * vm1; \
  } while (0)

  // ring: 7 pair-slots x 5 channels, split even/odd as SCALAR arrays (70 f32)
  float R1e[7], R1o[7], R2e[7], R2o[7], R11e[7], R11o[7], R22e[7], R22o[7],
      R12e[7], R12o[7];
  f32x2 accv = {0.f, 0.f};

  // prologue: stage pair0 into buf0; held <- pair1
  f32x2 hx0, hy0, hx1, hy1, nx0, ny0, nx1, ny1;
  PAIRLOAD(0, hx0, hy0, hx1, hy1);
  LSX[wid][0][lane] = hx0; LSY[wid][0][lane] = hy0;
  LSX[wid][0][64 + lane] = hx1; LSY[wid][0][64 + lane] = hy1;
  PAIRLOAD(1, hx0, hy0, hx1, hy1);

  for (int bl = 0; bl < 28; bl += 7) {
#pragma unroll
    for (int u = 0; u < 7; ++u) {
      const int li = bl + u;  // pair index; ring slot is `u` (bl % 7 == 0)
      if (li < NPAIR) {
        // (1) issue loads for pair li+2
        if (li + 2 < NPAIR) PAIRLOAD(li + 2, nx0, ny0, nx1, ny1);
        // (2) stage held pair li+1 into the other buffer
        if (li + 1 < NPAIR) {
          f32x2* wx = &LSX[wid][(li + 1) & 1][0];
          f32x2* wy = &LSY[wid][(li + 1) & 1][0];
          wx[lane] = hx0; wy[lane] = hy0;
          wx[64 + lane] = hx1; wy[64 + lane] = hy1;
        }
        // (3) packed horizontal 11-tap conv on row-pair li
        {
          const f32x2* bx = &LSX[wid][li & 1][lane];
          const f32x2* by = &LSY[wid][li & 1][lane];
          f32x2 s1 = {0, 0}, s2 = {0, 0}, s11 = {0, 0}, s22 = {0, 0},
                s12 = {0, 0};
#pragma unroll
          for (int k = 0; k < 11; ++k) {
            const f32x2 vx = bx[3 + k];
            const f32x2 vy = by[3 + k];
            const f32x2 tx = vx * WH[k];
            const f32x2 ty = vy * WH[k];
            s1 += tx; s2 += ty;
            s11 = fma2(tx, vx, s11);
            s22 = fma2(ty, vy, s22);
            s12 = fma2(tx, vy, s12);
          }
          const int ra = r0p + 2 * li;
          const float vr = ((unsigned)ra < IMG_H) ? 1.f : 0.f;
          const f32x2 vmr = {vr, vr};
          s1 *= vmr; s2 *= vmr; s11 *= vmr; s22 *= vmr; s12 *= vmr;
          // split into scalar even/odd ring slots (index u: compile-time)
          R1e[u] = s1.x;  R1o[u] = s1.y;
          R2e[u] = s2.x;  R2o[u] = s2.y;
          R11e[u] = s11.x; R11o[u] = s11.y;
          R22e[u] = s22.x; R22o[u] = s22.y;
          R12e[u] = s12.x; R12o[u] = s12.y;
        }
        // (4) scalar vertical conv + packed SSIM for out-pair i = li-6
        if (li >= 6) {
#define S_(m) ((u + 1 + (m)) % 7)
#define VERT(E, O, V0, V1)                              \
  do {                                                  \
    float v0_ = W0 * O[S_(0)];                          \
    v0_ = fmaf(W1, E[S_(1)], v0_);                      \
    v0_ = fmaf(W2, O[S_(1)], v0_);                      \
    v0_ = fmaf(W3, E[S_(2)], v0_);                      \
    v0_ = fmaf(W4, O[S_(2)], v0_);                      \
    v0_ = fmaf(W5, E[S_(3)], v0_);                      \
    v0_ = fmaf(W6, O[S_(3)], v0_);                      \
    v0_ = fmaf(W7, E[S_(4)], v0_);                      \
    v0_ = fmaf(W8, O[S_(4)], v0_);                      \
    v0_ = fmaf(W9, E[S_(5)], v0_);                      \
    v0_ = fmaf(W10, O[S_(5)], v0_);                     \
    V0 = v0_;                                           \
    float v1_ = W0 * E[S_(1)];                          \
    v1_ = fmaf(W1, O[S_(1)], v1_);                      \
    v1_ = fmaf(W2, E[S_(2)], v1_);                      \
    v1_ = fmaf(W3, O[S_(2)], v1_);                      \
    v1_ = fmaf(W4, E[S_(3)], v1_);                      \
    v1_ = fmaf(W5, O[S_(3)], v1_);                      \
    v1_ = fmaf(W6, E[S_(4)], v1_);                      \
    v1_ = fmaf(W7, O[S_(4)], v1_);                      \
    v1_ = fmaf(W8, E[S_(5)], v1_);                      \
    v1_ = fmaf(W9, O[S_(5)], v1_);                      \
    v1_ = fmaf(W10, E[S_(6)], v1_);                     \
    V1 = v1_;                                           \
  } while (0)
          float m1a, m1b, m2a, m2b, e11a, e11b, e22a, e22b, e12a, e12b;
          VERT(R1e, R1o, m1a, m1b);
          VERT(R2e, R2o, m2a, m2b);
          VERT(R11e, R11o, e11a, e11b);
          VERT(R22e, R22o, e22a, e22b);
          VERT(R12e, R12o, e12a, e12b);
#undef VERT
#undef S_
          const f32x2 m1 = {m1a, m1b}, m2 = {m2a, m2b};
          const f32x2 e11 = {e11a, e11b}, e22 = {e22a, e22b},
                      e12 = {e12a, e12b};
          const f32x2 c1v = {1e-4f, 1e-4f}, c2v = {9e-4f, 9e-4f};
          const f32x2 mu11 = m1 * m1, mu22 = m2 * m2, mu12 = m1 * m2;
          const f32x2 sg11 = e11 - mu11, sg22 = e22 - mu22, sg12 = e12 - mu12;
          const f32x2 num = (mu12 * 2.0f + c1v) * (sg12 * 2.0f + c2v);
          const f32x2 den = (mu11 + mu22 + c1v) * (sg11 + sg22 + c2v);
          float t0 = __builtin_amdgcn_rcpf(den.x);
          t0 = t0 * fmaf(-den.x, t0, 2.f);  // one Newton step
          float t1 = __builtin_amdgcn_rcpf(den.y);
          t1 = t1 * fmaf(-den.y, t1, 2.f);
          accv = fma2(num, (f32x2){t0, t1}, accv);
        }
        hx0 = nx0; hy0 = ny0; hx1 = nx1; hy1 = ny1;
      }
    }
  }

  // reduction: wave shuffle -> block LDS -> one atomic per block
  float tot = accv.x + accv.y;
  tot += __shfl_xor(tot, 1);
  tot += __shfl_xor(tot, 2);
  tot += __shfl_xor(tot, 4);
  tot += __shfl_xor(tot, 8);
  tot += __shfl_xor(tot, 16);
  tot += __shfl_xor(tot, 32);
  if (lane == 0) wsum[wid] = tot;
  __syncthreads();
  if (tid == 0) {
    const float s = wsum[0] + wsum[1] + wsum[2] + wsum[3];
    atomicAdd(out, s * (-1.0f / N_PIX));
  }
}

extern "C" void kernel_launch(void* const* d_in, const int* in_sizes, int n_in,
                              void* d_out, int out_size, void* d_ws,
                              size_t ws_size, hipStream_t stream) {
  const float* img1 = (const float*)d_in[0];
  const float* img2 = (const float*)d_in[1];
  float* out = (float*)d_out;
  ssim_init<<<1, 1, 0, stream>>>(out);
  ssim_main<<<1024, 256, 0, stream>>>(img1, img2, out);
}